// Round 2
// baseline (1559.284 us; speedup 1.0000x reference)
//
#include <hip/hip_runtime.h>

typedef unsigned int uint;
typedef unsigned short ushort;

#define D 128

__device__ __forceinline__ float bf2f(ushort h){ return __uint_as_float(((uint)h)<<16); }
__device__ __forceinline__ ushort f2bf(float f){
  uint u = __float_as_uint(f);
  u += 0x7fff + ((u >> 16) & 1);   // RNE
  return (ushort)(u >> 16);
}
// dtype-agnostic scalar load: bf==1 -> bf16 storage, bf==0 -> fp32 storage
__device__ __forceinline__ float ldf(const void* p, long i, int bf){
  return bf ? bf2f(((const ushort*)p)[i]) : ((const float*)p)[i];
}

// ---------------- dtype detection ----------------
// For bf16 storage, bits[14:7] of each 32-bit word are the LOW element's
// exponent field -> plausible range for N(0,1) data. For fp32 storage those
// bits are random mantissa -> in-range with p~0.21. Vote over 256 words.
__global__ __launch_bounds__(256) void detect_kernel(const uint* __restrict__ xw,
                                                     int* __restrict__ flag){
  __shared__ int cnt;
  if (threadIdx.x == 0) cnt = 0;
  __syncthreads();
  uint w = xw[threadIdx.x];
  int ef = (int)((w >> 7) & 0xffu);
  if (ef >= 90 && ef <= 142) atomicAdd(&cnt, 1);
  __syncthreads();
  if (threadIdx.x == 0) flag[0] = (cnt >= 128) ? 1 : 0;
}

// ---------------- edge message + scatter-add ----------------
// m = relu((x[src]+vn) + (edge_attr@W + b)); agg[dst] += m
template<bool FIRST>
__global__ __launch_bounds__(256) void edge_kernel(
    const int* __restrict__ src, const int* __restrict__ dst,
    const void* __restrict__ eattr,                 // [E,16]
    const void* __restrict__ ew,                    // [L,16,128]
    const void* __restrict__ eb,                    // [L,128]
    const void* __restrict__ vn,                    // [L,128]
    int layer,
    const void* __restrict__ xin,                   // [N,128] input-dtype (FIRST)
    const float* __restrict__ xws,                  // [N,128] fp32 ws (!FIRST)
    float* __restrict__ agg, int E_, const int* __restrict__ flag)
{
  int bf = flag[0];
  __shared__ float w[16][D];
  __shared__ float bb[D];
  __shared__ float vv[D];
  int tid = threadIdx.x;
  long wo = (long)layer*16*D;
  for (int i = tid; i < 16*D; i += 256) w[i>>7][i&127] = ldf(ew, wo + i, bf);
  if (tid < D){
    bb[tid] = ldf(eb, (long)layer*D + tid, bf);
    vv[tid] = ldf(vn, (long)layer*D + tid, bf);
  }
  __syncthreads();
  int half = tid >> 7, d = tid & 127;
  for (long e = (long)blockIdx.x*2 + half; e < E_; e += (long)gridDim.x*2){
    int s = src[e], t = dst[e];
    float av[16];
    if (bf){
      const uint4* ap = (const uint4*)((const ushort*)eattr + e*16);
      uint4 q0 = ap[0], q1 = ap[1];
      uint uu[8] = {q0.x,q0.y,q0.z,q0.w,q1.x,q1.y,q1.z,q1.w};
      #pragma unroll
      for (int j = 0; j < 8; j++){
        av[2*j]   = __uint_as_float(uu[j] << 16);
        av[2*j+1] = __uint_as_float(uu[j] & 0xffff0000u);
      }
    } else {
      const float4* ap = (const float4*)((const float*)eattr + e*16);
      float4 f0 = ap[0], f1 = ap[1], f2 = ap[2], f3 = ap[3];
      av[0]=f0.x; av[1]=f0.y; av[2]=f0.z; av[3]=f0.w;
      av[4]=f1.x; av[5]=f1.y; av[6]=f1.z; av[7]=f1.w;
      av[8]=f2.x; av[9]=f2.y; av[10]=f2.z; av[11]=f2.w;
      av[12]=f3.x; av[13]=f3.y; av[14]=f3.z; av[15]=f3.w;
    }
    float acc = bb[d];
    #pragma unroll
    for (int k = 0; k < 16; k++) acc += av[k]*w[k][d];
    float xv = FIRST ? ldf(xin, (long)s*D + d, bf) : xws[(long)s*D + d];
    float m = xv + vv[d] + acc;
    if (m > 0.f) unsafeAtomicAdd(&agg[(long)t*D + d], m);  // relu: skip zeros
  }
}

// ---------------- node GEMM 128->128 ----------------
// PRE:  in = (1+eps)*(x+vn) + agg   else in = x (fp32 ws)
template<bool PRE, bool FIRST, bool RELU>
__global__ __launch_bounds__(256) void mlp_kernel(
    const void* __restrict__ xin, const float* __restrict__ xws,
    const float* __restrict__ agg,
    const void* __restrict__ vn, const void* __restrict__ epsp, int layer,
    const void* __restrict__ W, const void* __restrict__ Bv,
    float* __restrict__ outp, int Nn, const int* __restrict__ flag)
{
  int bf = flag[0];
  __shared__ float w[D][D];       // 64 KB fp32 weights
  __shared__ float hrow[8][D];
  __shared__ float bias[D];
  __shared__ float vv[D];
  int tid = threadIdx.x;
  long wo = (long)layer*D*D;
  for (int i = tid; i < D*D; i += 256) w[i>>7][i&127] = ldf(W, wo + i, bf);
  if (tid < D){
    bias[tid] = ldf(Bv, (long)layer*D + tid, bf);
    vv[tid]   = PRE ? ldf(vn, (long)layer*D + tid, bf) : 0.f;
  }
  float epsv = PRE ? (1.f + ldf(epsp, layer, bf)) : 1.f;
  __syncthreads();
  int row = tid >> 5;              // 0..7
  int cg  = (tid & 31) << 2;       // col group of 4
  for (long base = (long)blockIdx.x*8; base < Nn; base += (long)gridDim.x*8){
    long r = base + row;
    bool valid = (r < Nn);
    if (valid){
      float4 hv;
      if (FIRST){
        if (bf){
          ushort4 u = *(const ushort4*)((const ushort*)xin + r*D + cg);
          hv = make_float4(bf2f(u.x),bf2f(u.y),bf2f(u.z),bf2f(u.w));
        } else {
          hv = *(const float4*)((const float*)xin + r*D + cg);
        }
      } else {
        hv = *(const float4*)(xws + r*D + cg);
      }
      if (PRE){
        float4 av = *(const float4*)(agg + r*D + cg);
        hv.x = epsv*(hv.x + vv[cg+0]) + av.x;
        hv.y = epsv*(hv.y + vv[cg+1]) + av.y;
        hv.z = epsv*(hv.z + vv[cg+2]) + av.z;
        hv.w = epsv*(hv.w + vv[cg+3]) + av.w;
      }
      *(float4*)&hrow[row][cg] = hv;
    }
    __syncthreads();
    float4 acc = make_float4(bias[cg],bias[cg+1],bias[cg+2],bias[cg+3]);
    #pragma unroll 16
    for (int k = 0; k < D; k++){
      float4 wv = *(const float4*)&w[k][cg];
      float h = hrow[row][k];
      acc.x += h*wv.x; acc.y += h*wv.y; acc.z += h*wv.z; acc.w += h*wv.w;
    }
    if (RELU){
      acc.x=fmaxf(acc.x,0.f); acc.y=fmaxf(acc.y,0.f);
      acc.z=fmaxf(acc.z,0.f); acc.w=fmaxf(acc.w,0.f);
    }
    if (valid) *(float4*)(outp + r*D + cg) = acc;
    __syncthreads();
  }
}

// ---------------- segment pool (batch is sorted) ----------------
__global__ __launch_bounds__(128) void pool_kernel(
    const float* __restrict__ x, const int* __restrict__ batch,
    int Nn, float* __restrict__ g, int colOff)
{
  int b = blockIdx.x, c = threadIdx.x;
  int lo = 0, hi = Nn;
  while (lo < hi){ int mid = (lo+hi)>>1; if (batch[mid] <  b) lo = mid+1; else hi = mid; }
  int start = lo;
  hi = Nn;
  while (lo < hi){ int mid = (lo+hi)>>1; if (batch[mid] <= b) lo = mid+1; else hi = mid; }
  int end = lo;
  float acc = 0.f;
  for (int r = start; r < end; r++) acc += x[(long)r*D + c];
  g[(long)b*384 + colOff + c] = acc;
}

// ---------------- head: Linear->LN->ReLU x2 -> Linear ----------------
__global__ __launch_bounds__(256) void head_kernel(
    const float* __restrict__ g,
    const void* __restrict__ w1, const void* __restrict__ b1,
    const void* __restrict__ g1, const void* __restrict__ be1,
    const void* __restrict__ w2, const void* __restrict__ b2,
    const void* __restrict__ g2, const void* __restrict__ be2,
    const void* __restrict__ ow, const void* __restrict__ ob,
    void* __restrict__ outp, const int* __restrict__ flag)
{
  int bf = flag[0];
  __shared__ float grow[384];
  __shared__ float h1[256];
  __shared__ float h2[128];
  __shared__ float redA[4], redB[4], stats[2];
  int b = blockIdx.x, tid = threadIdx.x;
  for (int i = tid; i < 384; i += 256) grow[i] = g[(long)b*384 + i];
  __syncthreads();
  // GEMM1: 384 -> 256
  float v = ldf(b1, tid, bf);
  for (int k = 0; k < 384; k++) v += grow[k] * ldf(w1, (long)k*256 + tid, bf);
  // LN over 256
  float s = v, s2 = v*v;
  for (int o = 32; o; o >>= 1){ s += __shfl_down(s,o); s2 += __shfl_down(s2,o); }
  if ((tid & 63) == 0){ redA[tid>>6] = s; redB[tid>>6] = s2; }
  __syncthreads();
  if (tid == 0){
    float S = redA[0]+redA[1]+redA[2]+redA[3];
    float S2 = redB[0]+redB[1]+redB[2]+redB[3];
    float mu = S / 256.f;
    stats[0] = mu; stats[1] = rsqrtf(S2/256.f - mu*mu + 1e-5f);
  }
  __syncthreads();
  float y = (v - stats[0]) * stats[1] * ldf(g1, tid, bf) + ldf(be1, tid, bf);
  h1[tid] = fmaxf(y, 0.f);
  __syncthreads();
  // GEMM2: 256 -> 128
  float v2 = 0.f;
  if (tid < 128){
    v2 = ldf(b2, tid, bf);
    for (int k = 0; k < 256; k++) v2 += h1[k] * ldf(w2, (long)k*128 + tid, bf);
  }
  float t = (tid < 128) ? v2 : 0.f;
  s = t; s2 = t*t;
  for (int o = 32; o; o >>= 1){ s += __shfl_down(s,o); s2 += __shfl_down(s2,o); }
  if ((tid & 63) == 0){ redA[tid>>6] = s; redB[tid>>6] = s2; }
  __syncthreads();
  if (tid == 0){
    float S = redA[0]+redA[1]+redA[2]+redA[3];
    float S2 = redB[0]+redB[1]+redB[2]+redB[3];
    float mu = S / 128.f;
    stats[0] = mu; stats[1] = rsqrtf(S2/128.f - mu*mu + 1e-5f);
  }
  __syncthreads();
  if (tid < 128){
    float y2 = (v2 - stats[0]) * stats[1] * ldf(g2, tid, bf) + ldf(be2, tid, bf);
    h2[tid] = fmaxf(y2, 0.f);
  }
  __syncthreads();
  float p = (tid < 128) ? h2[tid] * ldf(ow, tid, bf) : 0.f;
  s = p;
  for (int o = 32; o; o >>= 1) s += __shfl_down(s, o);
  if ((tid & 63) == 0) redA[tid>>6] = s;
  __syncthreads();
  if (tid == 0){
    float r = redA[0]+redA[1]+redA[2]+redA[3] + ldf(ob, 0, bf);
    if (bf) ((ushort*)outp)[b] = f2bf(r);
    else    ((float*)outp)[b]  = r;
  }
}

extern "C" void kernel_launch(void* const* d_in, const int* in_sizes, int n_in,
                              void* d_out, int out_size, void* d_ws, size_t ws_size,
                              hipStream_t stream)
{
  const void* x_in  = d_in[0];
  const int*  eidx  = (const int*)d_in[1];
  const void* eattr = d_in[2];
  const int*  batch = (const int*)d_in[3];
  const void* vn    = d_in[4];
  const void* ew    = d_in[5];
  const void* eb    = d_in[6];
  const void* epsp  = d_in[7];
  const void* w1p   = d_in[8];
  const void* b1p   = d_in[9];
  const void* w2p   = d_in[10];
  const void* b2p   = d_in[11];
  const void* lw1   = d_in[12];
  const void* lb1   = d_in[13];
  const void* ln1g  = d_in[14];
  const void* ln1b  = d_in[15];
  const void* lw2   = d_in[16];
  const void* lb2   = d_in[17];
  const void* ln2g  = d_in[18];
  const void* ln2b  = d_in[19];
  const void* owp   = d_in[20];
  const void* obp   = d_in[21];

  int Nn = in_sizes[0] / D;     // 50000
  int Ee = in_sizes[1] / 2;     // 600000
  int Gg = out_size;            // 512
  const int* srcp = eidx;
  const int* dstp = eidx + Ee;

  // ws layout (fp32): A[N*128] (agg, aliased as t1), B[N*128] (x ping-pong),
  // gbuf[G*384], flag
  float* A    = (float*)d_ws;
  float* B    = A + (size_t)Nn*D;
  float* gbuf = B + (size_t)Nn*D;
  int*   flag = (int*)(gbuf + (size_t)Gg*384);

  detect_kernel<<<1,256,0,stream>>>((const uint*)x_in, flag);

  for (int i = 0; i < 3; i++){
    hipMemsetAsync(A, 0, (size_t)Nn*D*sizeof(float), stream);
    if (i == 0)
      edge_kernel<true ><<<2048,256,0,stream>>>(srcp,dstp,eattr, ew, eb, vn, i,
                                                x_in, nullptr, A, Ee, flag);
    else
      edge_kernel<false><<<2048,256,0,stream>>>(srcp,dstp,eattr, ew, eb, vn, i,
                                                nullptr, B, A, Ee, flag);
    // MLP1 (PRE + relu): writes A in-place (same-row alias is barrier-safe)
    if (i == 0)
      mlp_kernel<true ,true ,true ><<<1024,256,0,stream>>>(x_in, nullptr, A, vn, epsp, i,
                                                           w1p, b1p, A, Nn, flag);
    else
      mlp_kernel<true ,false,true ><<<1024,256,0,stream>>>(nullptr, B, A, vn, epsp, i,
                                                           w1p, b1p, A, Nn, flag);
    // MLP2: A -> B (B's old content is dead by now)
    mlp_kernel<false,false,false><<<1024,256,0,stream>>>(nullptr, A, nullptr, vn, epsp, i,
                                                         w2p, b2p, B, Nn, flag);
    pool_kernel<<<Gg,128,0,stream>>>(B, batch, Nn, gbuf, i*D);
  }
  head_kernel<<<Gg,256,0,stream>>>(gbuf, lw1, lb1, ln1g, ln1b,
                                   lw2, lb2, ln2g, ln2b, owp, obp, d_out, flag);
}